// Round 5
// baseline (246.686 us; speedup 1.0000x reference)
//
#include <hip/hip_runtime.h>

// KAN-CNN: out[b,f,h,w] = sum_{dy,dx,c} R_{f,dy,dx,c}( xpad[b,c,h+dy-1,w+dx-1] )
// R(x) = P5(x)/(1+|x*Q(x)|), P5 Horner a0..a5, Q Horner b0..b3.
//
// R5: pk-friendly data layout. Each thread = ONE pixel; the two lanes of every
// v2f are channels (c, c+1) of that pixel. x pairs: two dword loads, each value
// used in exactly one pair position -> zero packing movs. Coefficient pairs:
// prologue re-layouts coefs to cT[f][k2][c/2][10][2] (80 B entries, 16 B
// aligned) read as float4 VMEM loads -> all pk operands are VGPRs (no 1-SGPR
// rule conflicts, no splat movs). Block=1024 (one f) keeps the 11.5 KB coef
// set L1-resident. Pre-padded [B,C,66,66] input keeps zero boundary logic.

typedef float v2f __attribute__((ext_vector_type(2)));

#define Bb 8
#define Cc 32
#define Hh 64
#define Ww 64
#define Ff 64

#define PW 66
#define PPLANE (PW * PW)
#define NPAD (Bb * Cc * PPLANE)
#define NCT (Ff * 9 * 16 * 20)   // 184320 floats

__global__ __launch_bounds__(256) void pad_kernel(
    const float* __restrict__ x,   // [B,C,64,64]
    float* __restrict__ xpad)      // [B,C,66,66]
{
    int idx = (int)blockIdx.x * 256 + (int)threadIdx.x;
    if (idx >= NPAD) return;
    int cell  = idx % PPLANE;
    int plane = idx / PPLANE;
    int hp = cell / PW;
    int wp = cell % PW;
    float v = 0.0f;
    if (hp >= 1 && hp <= Hh && wp >= 1 && wp <= Ww)
        v = x[(size_t)plane * (Hh * Ww) + (hp - 1) * Ww + (wp - 1)];
    xpad[idx] = v;
}

// cT[((f*9+k2)*16 + cp)*20 + j*2 + (c&1)],  j in 0..9 (0-5: a_j, 6-9: b_{j-6})
__global__ __launch_bounds__(256) void coefT_kernel(
    const float* __restrict__ ncf,   // [F,3,3,C,6]
    const float* __restrict__ dcf,   // [F,3,3,C,4]
    float* __restrict__ cT)
{
    int idx = (int)blockIdx.x * 256 + (int)threadIdx.x;
    if (idx >= NCT) return;
    int j  = idx % 10;
    int c  = (idx / 10) % 32;
    int fk = idx / 320;              // f*9 + k2
    float v = (j < 6) ? ncf[(fk * 32 + c) * 6 + j]
                      : dcf[(fk * 32 + c) * 4 + (j - 6)];
    cT[(fk * 16 + (c >> 1)) * 20 + j * 2 + (c & 1)] = v;
}

__global__ __launch_bounds__(1024) void kan_kernel(
    const float* __restrict__ xpad,  // [B,C,66,66] zero-bordered
    const float* __restrict__ cT,    // [F,9,16,10,2]
    float* __restrict__ out)         // [B,F,H,W]
{
    const int t  = threadIdx.x;
    const int w  = t & 63;
    const int rr = t >> 6;                      // 0..15
    const int h  = (int)blockIdx.y * 16 + rr;
    const int f  = (int)blockIdx.x;
    const int b  = (int)blockIdx.z;

    // tap (dy,dx) of pixel (h,w) lives at padded (h+dy, w+dx)
    const float* __restrict__ xp = xpad + (size_t)b * Cc * PPLANE + h * PW + w;
    const float* __restrict__ cf = cT + (size_t)f * 9 * 16 * 20;

    v2f acc = {0.0f, 0.0f};

    for (int cp = 0; cp < 16; ++cp) {
        const float* __restrict__ x0 = xp + (2 * cp) * PPLANE;
        // 9 tap pairs {c=2cp, c=2cp+1}; each scalar used in exactly one slot.
        v2f xv[9];
#pragma unroll
        for (int dy = 0; dy < 3; ++dy)
#pragma unroll
            for (int dx = 0; dx < 3; ++dx) {
                v2f v;
                v.x = x0[dy * PW + dx];
                v.y = x0[PPLANE + dy * PW + dx];
                xv[dy * 3 + dx] = v;
            }

        const float4* __restrict__ cc4 = (const float4*)(cf + cp * 20);
#pragma unroll
        for (int k2 = 0; k2 < 9; ++k2) {
            const float4* __restrict__ q = cc4 + k2 * 80;   // (k2*16)*20/4
            const float4 q0 = q[0], q1 = q[1], q2 = q[2], q3 = q[3], q4 = q[4];
            const v2f a0 = {q0.x, q0.y}, a1 = {q0.z, q0.w};
            const v2f a2 = {q1.x, q1.y}, a3 = {q1.z, q1.w};
            const v2f a4 = {q2.x, q2.y}, a5 = {q2.z, q2.w};
            const v2f b0 = {q3.x, q3.y}, b1 = {q3.z, q3.w};
            const v2f b2 = {q4.x, q4.y}, b3 = {q4.z, q4.w};

            const v2f x = xv[k2];
            v2f n = __builtin_elementwise_fma(x, a5, a4);
            n = __builtin_elementwise_fma(n, x, a3);
            n = __builtin_elementwise_fma(n, x, a2);
            n = __builtin_elementwise_fma(n, x, a1);
            n = __builtin_elementwise_fma(n, x, a0);
            v2f qq = __builtin_elementwise_fma(x, b3, b2);
            qq = __builtin_elementwise_fma(qq, x, b1);
            qq = __builtin_elementwise_fma(qq, x, b0);
            const v2f tt = qq * x;
            v2f r;
            r.x = __builtin_amdgcn_rcpf(1.0f + __builtin_fabsf(tt.x));
            r.y = __builtin_amdgcn_rcpf(1.0f + __builtin_fabsf(tt.y));
            acc = __builtin_elementwise_fma(n, r, acc);
        }
    }

    out[(((size_t)b * Ff + f) * Hh + h) * Ww + w] = acc.x + acc.y;
}

extern "C" void kernel_launch(void* const* d_in, const int* in_sizes, int n_in,
                              void* d_out, int out_size, void* d_ws, size_t ws_size,
                              hipStream_t stream) {
    const float* x   = (const float*)d_in[0];
    const float* ncf = (const float*)d_in[1];
    const float* dcf = (const float*)d_in[2];
    float* out  = (float*)d_out;
    float* xpad = (float*)d_ws;                 // 4.46 MB
    float* cT   = (float*)d_ws + NPAD;          // +0.74 MB

    pad_kernel<<<(NPAD + 255) / 256, 256, 0, stream>>>(x, xpad);
    coefT_kernel<<<(NCT + 255) / 256, 256, 0, stream>>>(ncf, dcf, cT);

    dim3 grid(Ff, Hh / 16, Bb);
    kan_kernel<<<grid, dim3(1024), 0, stream>>>(xpad, cT, out);
}

// Round 7
// 219.050 us; speedup vs baseline: 1.1262x; 1.1262x over previous
//
#include <hip/hip_runtime.h>

// KAN-CNN via MFMA: out[b,f,h,w] = sum_{k2,c} P5(x)/(1+|x*Q(x)|), x = xpad tap.
// Key factorization: for fixed (c,k2), num[px,f] = sum_j a_j[f] * x^j[px] and
// t[px,f] = x*Q = sum_{j=1..4} b_{j-1}[f] * x^j[px] are 16x16x(K=6) matmuls
// sharing one A-fragment (f16 powers of x, fp32-computed then rounded once).
// MFMA f32_16x16x32_f16, fp32 accumulate. Only 1+|t|, rcp, num*r, acc stay on
// VALU/trans (~4x less VALU than the scalar plateau; pk-fp32 is NOT 2x on
// CDNA4 — 157.3 TF spec = scalar rate).
// Layouts (guide-verified m89/m120): A[m=lane&15][k=(lane>>4)*8+j],
// C/D col(=f)=lane&15, row(=px)=(lane>>4)*4+reg.

typedef _Float16 v8h __attribute__((ext_vector_type(8)));
typedef __fp16   h2  __attribute__((ext_vector_type(2)));   // cvt_pkrtz return type
typedef float    v4f __attribute__((ext_vector_type(4)));

#define Bb 8
#define Cc 32
#define Hh 64
#define Ww 64
#define Ff 64
#define PW 66
#define PPLANE (PW * PW)
#define NPAD (Bb * Cc * PPLANE)
#define NBF (4 * 32 * 9 * 2 * 64)   // v8h fragment entries = 147456

__global__ __launch_bounds__(256) void pad_kernel(
    const float* __restrict__ x, float* __restrict__ xpad)
{
    int idx = (int)blockIdx.x * 256 + (int)threadIdx.x;
    if (idx >= NPAD) return;
    int cell  = idx % PPLANE;
    int plane = idx / PPLANE;
    int hp = cell / PW, wp = cell % PW;
    float v = 0.0f;
    if (hp >= 1 && hp <= Hh && wp >= 1 && wp <= Ww)
        v = x[(size_t)plane * (Hh * Ww) + (hp - 1) * Ww + (wp - 1)];
    xpad[idx] = v;
}

// Pre-bake B fragments: bfrag[(((ftile*32+c)*9+k2)*2+which)*64+lane] = 8 f16.
// B[k][n]: n = lane&15 (f within tile), k = (lane>>4)*8 + i.
// which=0 (num): B[k] = a_k for k<6 else 0.  which=1 (den): B[k] = b_{k-1} for 1<=k<=4.
__global__ __launch_bounds__(256) void bfrag_kernel(
    const float* __restrict__ ncf,   // [F,3,3,C,6]
    const float* __restrict__ dcf,   // [F,3,3,C,4]
    v8h* __restrict__ bfrag)
{
    int idx = (int)blockIdx.x * 256 + (int)threadIdx.x;
    if (idx >= NBF) return;
    int lane = idx & 63;
    int tmp  = idx >> 6;
    int which = tmp & 1; tmp >>= 1;
    int k2 = tmp % 9;    tmp /= 9;
    int c  = tmp & 31;   tmp >>= 5;
    int ftile = tmp;                       // 0..3
    int f  = ftile * 16 + (lane & 15);
    int kb = (lane >> 4) * 8;
    size_t cb = ((size_t)(f * 9 + k2) * 32 + c);
    const float* a6 = ncf + cb * 6;
    const float* b4 = dcf + cb * 4;
    v8h v;
#pragma unroll
    for (int i = 0; i < 8; ++i) {
        int k = kb + i;
        float val = (which == 0) ? ((k < 6) ? a6[k] : 0.0f)
                                 : ((k >= 1 && k <= 4) ? b4[k - 1] : 0.0f);
        v[i] = (_Float16)val;
    }
    bfrag[idx] = v;
}

__global__ __launch_bounds__(256) void kan_kernel(
    const float* __restrict__ xpad,   // [B,C,66,66] zero-bordered
    const v8h*  __restrict__ bfrag,   // [4,32,9,2,64] fragments
    float* __restrict__ out)          // [B,F,H,W]
{
    const int t = threadIdx.x;
    const int l = t & 63;
    const int wid   = (int)blockIdx.x * 4 + (t >> 6);
    const int ftile = wid & 3;
    const int slab  = wid >> 2;            // 0..1023
    const int p0 = slab * 32;              // 2 px-tiles of 16 (same b,h row)
    const int b  = p0 >> 12;
    const int h  = (p0 >> 6) & 63;
    const int w0 = p0 & 63;                // 0 or 32
    const int m  = l & 15;
    const bool alo = (l < 16);             // lanes holding k=0..7 (only k<6 used)

    const v4f zz = {0.0f, 0.0f, 0.0f, 0.0f};
    v4f acc0 = zz, acc1 = zz;

    const v8h* __restrict__ bf = bfrag + (size_t)ftile * (32 * 9 * 2 * 64) + l;
    const float* __restrict__ xb =
        xpad + (size_t)b * Cc * PPLANE + h * PW + w0;

    for (int c = 0; c < Cc; ++c) {
        const float* __restrict__ xc = xb + c * PPLANE;
#pragma unroll
        for (int dy = 0; dy < 3; ++dy) {
#pragma unroll
            for (int dx = 0; dx < 3; ++dx) {
                const int k2 = dy * 3 + dx;
                const v8h bn = bf[((c * 9 + k2) * 2 + 0) * 64];
                const v8h bd = bf[((c * 9 + k2) * 2 + 1) * 64];
#pragma unroll
                for (int tt = 0; tt < 2; ++tt) {
                    const float xv = xc[dy * PW + dx + m + 16 * tt];
                    const float x2 = xv * xv, x3 = x2 * xv;
                    const float x4 = x2 * x2, x5 = x4 * xv;
                    union { v8h v; h2 q[4]; unsigned u[4]; } A;
                    A.q[0] = __builtin_amdgcn_cvt_pkrtz(1.0f, xv);
                    A.q[1] = __builtin_amdgcn_cvt_pkrtz(x2, x3);
                    A.q[2] = __builtin_amdgcn_cvt_pkrtz(x4, x5);
                    A.u[3] = 0u;
                    if (!alo) { A.u[0] = 0u; A.u[1] = 0u; A.u[2] = 0u; }

                    v4f td = __builtin_amdgcn_mfma_f32_16x16x32_f16(A.v, bd, zz, 0, 0, 0);
                    v4f tn = __builtin_amdgcn_mfma_f32_16x16x32_f16(A.v, bn, zz, 0, 0, 0);

                    v4f& acc = tt ? acc1 : acc0;
#pragma unroll
                    for (int r = 0; r < 4; ++r) {
                        const float den = 1.0f + __builtin_fabsf(td[r]);
                        acc[r] += tn[r] * __builtin_amdgcn_rcpf(den);
                    }
                }
            }
        }
    }

    // C/D: f = ftile*16 + (l&15); px(w-offset) = (l>>4)*4 + r  (+16 for tile1)
    const int fcol = ftile * 16 + m;
    const int prow = (l >> 4) * 4;
    float* __restrict__ ob =
        out + (((size_t)b * Ff + fcol) * Hh + h) * Ww + w0 + prow;
#pragma unroll
    for (int r = 0; r < 4; ++r) {
        ob[r]      = acc0[r];
        ob[16 + r] = acc1[r];
    }
}

extern "C" void kernel_launch(void* const* d_in, const int* in_sizes, int n_in,
                              void* d_out, int out_size, void* d_ws, size_t ws_size,
                              hipStream_t stream) {
    const float* x   = (const float*)d_in[0];
    const float* ncf = (const float*)d_in[1];
    const float* dcf = (const float*)d_in[2];
    float* out  = (float*)d_out;
    float* xpad = (float*)d_ws;                          // 4.46 MB
    v8h*   bfrag = (v8h*)((char*)d_ws + (size_t)NPAD * 4); // +2.36 MB

    pad_kernel<<<(NPAD + 255) / 256, 256, 0, stream>>>(x, xpad);
    bfrag_kernel<<<(NBF + 255) / 256, 256, 0, stream>>>(ncf, dcf, bfrag);

    kan_kernel<<<dim3(1024), dim3(256), 0, stream>>>(xpad, bfrag, out);
}